// Round 6
// baseline (411.029 us; speedup 1.0000x reference)
//
#include <hip/hip_runtime.h>
#include <hip/hip_cooperative_groups.h>
#include <math.h>

namespace cg = cooperative_groups;

#define N_NODES 100000
#define N_EDGES 1600000
#define IN_DIM  256
#define HIDDEN  64

// ---- mega-kernel geometry ---------------------------------------------------
#define GRID    512
#define TPB     512
// phase 1 degree: 256 blocks = 32 chunks x 8 ranges, byte-packed u32
#define D_NB    32
#define D_EPB   50000
#define D_QPB   12500      // int4 groups per chunk
#define D_PD    8
#define D_DNR   12800
#define D_DW    3200       // packed words per range (12.8 KB LDS)
// phase 3 scatter: 512 blocks = 64 chunks x 8 ranges
#define S_NB    64
#define S_EPB   25000
#define S_QPB   6250       // int4 groups per chunk
#define S_SR    8
#define S_RANGE 12544      // floats per range (50,176 B LDS)

// ---------------------------------------------------------------------------
// Cooperative mega-kernel: deg-hist + s  ->  deg-merge  ->  scatter  ->  final
// All phases in one launch; grid.sync() between them. 512 blocks x 512 thr,
// 2 blocks/CU co-resident (VGPR<=128 via launch_bounds, LDS 50KB).
// ---------------------------------------------------------------------------
__global__ void __launch_bounds__(TPB, 4) mega_kernel(
    const float* __restrict__ x, const float* __restrict__ W,
    const float* __restrict__ b, const float* __restrict__ w2,
    const float* __restrict__ b2,
    const int4* __restrict__ src4, const int4* __restrict__ dst4,
    float* __restrict__ s, float* __restrict__ dinv, float* __restrict__ t,
    unsigned* __restrict__ partialD, float* __restrict__ partialU,
    float* __restrict__ out)
{
    __shared__ __align__(16) float sh[S_RANGE];   // 50,176 B, reused per phase
    cg::grid_group grid = cg::this_grid();
    const int bid = blockIdx.x;
    const int tid = threadIdx.x;

    // ---------------- Phase 1: degree histogram (blocks 0..255) ||
    //                  s[n] = x[n].v (blocks 256..511) ----------------------
    if (bid < 256) {
        unsigned* hist = (unsigned*)sh;
        const int r  = bid & 7;             // D_PD == 8
        const int bb = bid >> 3;
        const int nbase = r * D_DNR;
        for (int i = tid; i < D_DW; i += TPB) hist[i] = 0u;
        __syncthreads();
        const int q0 = bb * D_QPB;
        for (int k = tid; k < D_QPB; k += TPB) {
            int4 d4 = dst4[q0 + k];
            int d0 = d4.x - nbase, d1 = d4.y - nbase, d2 = d4.z - nbase, d3 = d4.w - nbase;
            if ((unsigned)d0 < (unsigned)D_DNR) atomicAdd(&hist[d0 >> 2], 1u << ((d0 & 3) * 8));
            if ((unsigned)d1 < (unsigned)D_DNR) atomicAdd(&hist[d1 >> 2], 1u << ((d1 & 3) * 8));
            if ((unsigned)d2 < (unsigned)D_DNR) atomicAdd(&hist[d2 >> 2], 1u << ((d2 & 3) * 8));
            if ((unsigned)d3 < (unsigned)D_DNR) atomicAdd(&hist[d3 >> 2], 1u << ((d3 & 3) * 8));
        }
        __syncthreads();
        unsigned* outp = partialD + (size_t)bid * D_DW;
        for (int i = tid; i < D_DW; i += TPB) outp[i] = hist[i];
    } else {
        // v = W @ w2 computed per block into LDS (W is 64KB, L2-hot)
        if (tid < IN_DIM) {
            const float4* wr  = (const float4*)(W + tid * HIDDEN);
            const float4* w2r = (const float4*)w2;
            float acc = 0.f;
            #pragma unroll
            for (int j = 0; j < HIDDEN / 4; ++j) {
                float4 a = wr[j], q = w2r[j];
                acc += a.x * q.x + a.y * q.y + a.z * q.z + a.w * q.w;
            }
            sh[tid] = acc;
        }
        __syncthreads();
        const int wid  = tid >> 6;
        const int lane = tid & 63;
        float4 vv = ((const float4*)sh)[lane];
        int gw = (bid - 256) * (TPB / 64) + wid;   // 0..2047
        for (int n = gw; n < N_NODES; n += 2048) {
            const float4* xr = (const float4*)(x + (size_t)n * IN_DIM);
            float4 a = xr[lane];
            float d = a.x * vv.x + a.y * vv.y + a.z * vv.z + a.w * vv.w;
            #pragma unroll
            for (int off = 32; off > 0; off >>= 1) d += __shfl_down(d, off, 64);
            if (lane == 0) s[n] = d;
        }
    }
    grid.sync();

    // ---------------- Phase 2: deg merge -> dinv, t = dinv*s ----------------
    {
        int w = bid * TPB + tid;
        if (w < N_NODES / 4) {
            const int r = w / D_DW, j = w - r * D_DW;
            unsigned a0 = 0, a1 = 0, a2 = 0, a3 = 0;
            #pragma unroll 8
            for (int bb = 0; bb < D_NB; ++bb) {
                unsigned p = partialD[(size_t)(bb * D_PD + r) * D_DW + j];
                a0 += p & 255u; a1 += (p >> 8) & 255u; a2 += (p >> 16) & 255u; a3 += p >> 24;
            }
            const int n0 = w * 4;
            float4 sv = *(const float4*)(s + n0);
            float4 di, tv;
            di.x = rsqrtf((float)(a0 + 1)); di.y = rsqrtf((float)(a1 + 1));
            di.z = rsqrtf((float)(a2 + 1)); di.w = rsqrtf((float)(a3 + 1));
            tv.x = di.x * sv.x; tv.y = di.y * sv.y; tv.z = di.z * sv.z; tv.w = di.w * sv.w;
            *(float4*)(dinv + n0) = di;
            *(float4*)(t + n0) = tv;
        }
    }
    grid.sync();

    // ---------------- Phase 3: LDS-private scatter --------------------------
    {
        float* acc = sh;
        const int r  = bid & 7;             // S_SR == 8
        const int bb = bid >> 3;
        const int nbase = r * S_RANGE;
        for (int i = tid; i < S_RANGE; i += TPB) acc[i] = 0.f;
        __syncthreads();
        const int q0 = bb * S_QPB;
        for (int k = tid; k < S_QPB; k += TPB) {
            int4 d4 = dst4[q0 + k];
            int4 s4 = src4[q0 + k];
            int d0 = d4.x - nbase, d1 = d4.y - nbase, d2 = d4.z - nbase, d3 = d4.w - nbase;
            if ((unsigned)d0 < (unsigned)S_RANGE) atomicAdd(&acc[d0], t[s4.x]);
            if ((unsigned)d1 < (unsigned)S_RANGE) atomicAdd(&acc[d1], t[s4.y]);
            if ((unsigned)d2 < (unsigned)S_RANGE) atomicAdd(&acc[d2], t[s4.z]);
            if ((unsigned)d3 < (unsigned)S_RANGE) atomicAdd(&acc[d3], t[s4.w]);
        }
        __syncthreads();
        float* outp = partialU + (size_t)bid * S_RANGE;
        for (int i = tid; i < S_RANGE; i += TPB) outp[i] = acc[i];
    }
    grid.sync();

    // ---------------- Phase 4: merge partials + sigmoid ---------------------
    {
        float c = b2[0];
        #pragma unroll 8
        for (int j = 0; j < HIDDEN; ++j) c += b[j] * w2[j];
        int n = bid * TPB + tid;
        if (n < N_NODES) {
            const int r = n / S_RANGE, j = n - r * S_RANGE;
            float u = 0.f;
            #pragma unroll 8
            for (int bl = 0; bl < S_NB; ++bl)
                u += partialU[(size_t)(bl * S_SR + r) * S_RANGE + j];
            float di = dinv[n];
            float pre = di * (u + di * s[n]) + c;
            out[n] = 1.f / (1.f + expf(-pre));
        }
    }
}

// ======================= fallback: R5 4-kernel path (validated) =============
#define NB      32
#define EPB     50000
#define QPB     12500
#define SR      8
#define SRANGE  12544
#define PD      8
#define DNR     12800
#define DW      3200
#define DEGB    256

__global__ void __launch_bounds__(1024) fusedA_kernel(const float* __restrict__ x,
                                                      const float* __restrict__ W,
                                                      const float* __restrict__ w2,
                                                      const int4* __restrict__ dst4,
                                                      unsigned* __restrict__ partialD,
                                                      float* __restrict__ s) {
    __shared__ __align__(16) unsigned sh[DW];
    const int bid = blockIdx.x;
    if (bid < DEGB) {
        const int r  = bid & (PD - 1);
        const int bb = bid >> 3;
        const int nbase = r * DNR;
        for (int i = threadIdx.x; i < DW; i += 1024) sh[i] = 0u;
        __syncthreads();
        const int q0 = bb * QPB;
        for (int k = threadIdx.x; k < QPB; k += 1024) {
            int4 d4 = dst4[q0 + k];
            int d0 = d4.x - nbase, d1 = d4.y - nbase, d2 = d4.z - nbase, d3 = d4.w - nbase;
            if ((unsigned)d0 < (unsigned)DNR) atomicAdd(&sh[d0 >> 2], 1u << ((d0 & 3) * 8));
            if ((unsigned)d1 < (unsigned)DNR) atomicAdd(&sh[d1 >> 2], 1u << ((d1 & 3) * 8));
            if ((unsigned)d2 < (unsigned)DNR) atomicAdd(&sh[d2 >> 2], 1u << ((d2 & 3) * 8));
            if ((unsigned)d3 < (unsigned)DNR) atomicAdd(&sh[d3 >> 2], 1u << ((d3 & 3) * 8));
        }
        __syncthreads();
        unsigned* outp = partialD + (size_t)bid * DW;
        for (int i = threadIdx.x; i < DW; i += 1024) outp[i] = sh[i];
    } else {
        float* vsh = (float*)sh;
        if (threadIdx.x < IN_DIM) {
            const float4* wr  = (const float4*)(W + threadIdx.x * HIDDEN);
            const float4* w2r = (const float4*)w2;
            float acc = 0.f;
            #pragma unroll
            for (int j = 0; j < HIDDEN / 4; ++j) {
                float4 a = wr[j], q = w2r[j];
                acc += a.x * q.x + a.y * q.y + a.z * q.z + a.w * q.w;
            }
            vsh[threadIdx.x] = acc;
        }
        __syncthreads();
        const int wid  = threadIdx.x >> 6;
        const int lane = threadIdx.x & 63;
        const int gw   = (bid - DEGB) * 16 + wid;
        float4 vv = ((const float4*)vsh)[lane];
        for (int n = gw; n < N_NODES; n += 4096) {
            const float4* xr = (const float4*)(x + (size_t)n * IN_DIM);
            float4 a = xr[lane];
            float d = a.x * vv.x + a.y * vv.y + a.z * vv.z + a.w * vv.w;
            #pragma unroll
            for (int off = 32; off > 0; off >>= 1) d += __shfl_down(d, off, 64);
            if (lane == 0) s[n] = d;
        }
    }
}

__global__ void deg_merge_kernel(const unsigned* __restrict__ partialD,
                                 const float* __restrict__ s,
                                 float* __restrict__ dinv, float* __restrict__ t) {
    int w = blockIdx.x * blockDim.x + threadIdx.x;
    if (w >= N_NODES / 4) return;
    const int r = w / DW, j = w - r * DW;
    unsigned a0 = 0, a1 = 0, a2 = 0, a3 = 0;
    #pragma unroll 8
    for (int b = 0; b < NB; ++b) {
        unsigned p = partialD[(size_t)(b * PD + r) * DW + j];
        a0 += p & 255u; a1 += (p >> 8) & 255u; a2 += (p >> 16) & 255u; a3 += p >> 24;
    }
    const int n0 = w * 4;
    float4 sv = *(const float4*)(s + n0);
    float4 di, tv;
    di.x = rsqrtf((float)(a0 + 1)); di.y = rsqrtf((float)(a1 + 1));
    di.z = rsqrtf((float)(a2 + 1)); di.w = rsqrtf((float)(a3 + 1));
    tv.x = di.x * sv.x; tv.y = di.y * sv.y; tv.z = di.z * sv.z; tv.w = di.w * sv.w;
    *(float4*)(dinv + n0) = di;
    *(float4*)(t + n0) = tv;
}

__global__ void __launch_bounds__(1024) scat_hist_kernel(const int4* __restrict__ src4,
                                                         const int4* __restrict__ dst4,
                                                         const float* __restrict__ t,
                                                         float* __restrict__ partialU) {
    __shared__ float acc[SRANGE];
    const int r  = blockIdx.x & (SR - 1);
    const int bb = blockIdx.x >> 3;
    const int nbase = r * SRANGE;
    for (int i = threadIdx.x; i < SRANGE; i += 1024) acc[i] = 0.f;
    __syncthreads();
    const int q0 = bb * QPB;
    for (int k = threadIdx.x; k < QPB; k += 1024) {
        int4 d4 = dst4[q0 + k];
        int4 s4 = src4[q0 + k];
        int d0 = d4.x - nbase, d1 = d4.y - nbase, d2 = d4.z - nbase, d3 = d4.w - nbase;
        if ((unsigned)d0 < (unsigned)SRANGE) atomicAdd(&acc[d0], t[s4.x]);
        if ((unsigned)d1 < (unsigned)SRANGE) atomicAdd(&acc[d1], t[s4.y]);
        if ((unsigned)d2 < (unsigned)SRANGE) atomicAdd(&acc[d2], t[s4.z]);
        if ((unsigned)d3 < (unsigned)SRANGE) atomicAdd(&acc[d3], t[s4.w]);
    }
    __syncthreads();
    float* outp = partialU + (size_t)blockIdx.x * SRANGE;
    for (int i = threadIdx.x; i < SRANGE; i += 1024) outp[i] = acc[i];
}

__global__ void merge_final_kernel(const float* __restrict__ partialU,
                                   const float* __restrict__ dinv,
                                   const float* __restrict__ s,
                                   const float* __restrict__ b,
                                   const float* __restrict__ w2,
                                   const float* __restrict__ b2,
                                   float* __restrict__ out) {
    float c = b2[0];
    #pragma unroll 8
    for (int j = 0; j < HIDDEN; ++j) c += b[j] * w2[j];
    int n = blockIdx.x * blockDim.x + threadIdx.x;
    if (n >= N_NODES) return;
    const int r = n / SRANGE, j = n - r * SRANGE;
    float u = 0.f;
    #pragma unroll 8
    for (int bl = 0; bl < NB; ++bl)
        u += partialU[(size_t)(bl * SR + r) * SRANGE + j];
    float di = dinv[n];
    float pre = di * (u + di * s[n]) + c;
    out[n] = 1.f / (1.f + expf(-pre));
}
// ============================================================================

extern "C" void kernel_launch(void* const* d_in, const int* in_sizes, int n_in,
                              void* d_out, int out_size, void* d_ws, size_t ws_size,
                              hipStream_t stream) {
    const float* x   = (const float*)d_in[0];   // [N, 256]
    const int*   ei  = (const int*)  d_in[1];   // [2, E]: src then dst
    const float* W   = (const float*)d_in[2];   // [256, 64]
    const float* b   = (const float*)d_in[3];   // [64]
    const float* w2  = (const float*)d_in[4];   // [64]
    const float* b2  = (const float*)d_in[5];   // [1]
    float* out = (float*)d_out;

    const int4* src4 = (const int4*)ei;
    const int4* dst4 = (const int4*)(ei + N_EDGES);

    float* ws = (float*)d_ws;
    float*    s        = ws + 512;      // 100000
    float*    t        = ws + 100608;   // 100000
    float*    dinv     = ws + 200704;   // 100000
    unsigned* partialD = (unsigned*)(ws + 300800);  // 256*3200  =   819,200 words
    float*    partialU = ws + 1120000;              // mega: 512*12544 = 6,422,528 floats
    const size_t mega_need  = (size_t)(1120000 + GRID * S_RANGE) * 4;  // ~30.2 MB
    const size_t fused_need = (size_t)(1120000 + 256 * SRANGE) * 4;    // ~17.3 MB

    bool done = false;
    if (ws_size >= mega_need) {
        void* args[] = {(void*)&x, (void*)&W, (void*)&b, (void*)&w2, (void*)&b2,
                        (void*)&src4, (void*)&dst4,
                        (void*)&s, (void*)&dinv, (void*)&t,
                        (void*)&partialD, (void*)&partialU, (void*)&out};
        hipError_t err = hipLaunchCooperativeKernel((void*)mega_kernel,
                                                    dim3(GRID), dim3(TPB),
                                                    args, 0, stream);
        done = (err == hipSuccess);
    }

    if (!done && ws_size >= fused_need) {
        fusedA_kernel<<<DEGB + 256, 1024, 0, stream>>>(x, W, w2, dst4, partialD, s);
        deg_merge_kernel<<<(N_NODES / 4 + 255) / 256, 256, 0, stream>>>(partialD, s, dinv, t);
        scat_hist_kernel<<<NB * SR, 1024, 0, stream>>>(src4, dst4, t, partialU);
        merge_final_kernel<<<(N_NODES + 511) / 512, 512, 0, stream>>>(partialU, dinv, s, b, w2, b2, out);
        done = true;
    }
}

// Round 7
// 306.576 us; speedup vs baseline: 1.3407x; 1.3407x over previous
//
#include <hip/hip_runtime.h>
#include <math.h>

#define N_NODES 100000
#define N_EDGES 1600000
#define IN_DIM  256
#define HIDDEN  64
#define NXCD    8
#define PAD     100352     // per-shard stride (>= N_NODES, 16-aligned)
#define EQ4     400000     // N_EDGES/4 int4 groups

// Physical XCD id of the executing wave [measured: learn_hip m09 on MI355X].
// Used only for performance sharding — any value 0..7 keeps results correct.
__device__ __forceinline__ int xcc_id() {
    unsigned id;
    asm volatile("s_getreg_b32 %0, hwreg(HW_REG_XCC_ID)" : "=s"(id));
    return (int)(id & (NXCD - 1));
}

// ---------------------------------------------------------------------------
// K1 (fused): per-block v = W.w2 in LDS; per-thread one int4 of dst ->
// 4 degree atomics into the XCD-local shard (L2-resident, no cross-XCD
// contention); then wave-per-row s[n] = x[n].v streaming (HBM-bound, hides
// the atomic latency machine-wide).
// ---------------------------------------------------------------------------
__global__ void __launch_bounds__(1024) k1_deg_s(const float* __restrict__ x,
                                                 const float* __restrict__ W,
                                                 const float* __restrict__ w2,
                                                 const int4* __restrict__ dst4,
                                                 int* __restrict__ degX,
                                                 float* __restrict__ s) {
    __shared__ __align__(16) float vsh[IN_DIM];
    const int tid = threadIdx.x, bid = blockIdx.x;

    // v = W @ w2 (W 64KB, L2-hot across blocks)
    if (tid < IN_DIM) {
        const float4* wr  = (const float4*)(W + tid * HIDDEN);
        const float4* w2r = (const float4*)w2;
        float acc = 0.f;
        #pragma unroll
        for (int j = 0; j < HIDDEN / 4; ++j) {
            float4 a = wr[j], q = w2r[j];
            acc += a.x * q.x + a.y * q.y + a.z * q.z + a.w * q.w;
        }
        vsh[tid] = acc;
    }

    // degree atomics: one int4 of dst per thread, into this XCD's shard
    {
        int gid = bid * 1024 + tid;
        if (gid < EQ4) {
            int4 d4 = dst4[gid];
            int* mydeg = degX + xcc_id() * PAD;
            atomicAdd(&mydeg[d4.x], 1);
            atomicAdd(&mydeg[d4.y], 1);
            atomicAdd(&mydeg[d4.z], 1);
            atomicAdd(&mydeg[d4.w], 1);
        }
    }
    __syncthreads();

    // s = x @ v : one wave per 1 KiB row (64 lanes x float4)
    const int wid  = tid >> 6;
    const int lane = tid & 63;
    float4 vv = ((const float4*)vsh)[lane];
    for (int n = bid * 16 + wid; n < N_NODES; n += 512 * 16) {
        const float4* xr = (const float4*)(x + (size_t)n * IN_DIM);
        float4 a = xr[lane];
        float d = a.x * vv.x + a.y * vv.y + a.z * vv.z + a.w * vv.w;
        #pragma unroll
        for (int off = 32; off > 0; off >>= 1) d += __shfl_down(d, off, 64);
        if (lane == 0) s[n] = d;
    }
}

// ---------------------------------------------------------------------------
// K2: merge 8 degree shards -> dinv = rsqrt(deg+1), t = dinv*s.
// 8 coalesced strided streams (3.2 MB total).
// ---------------------------------------------------------------------------
__global__ void k2_deg_merge(const int* __restrict__ degX,
                             const float* __restrict__ s,
                             float* __restrict__ dinv, float* __restrict__ t) {
    int n = blockIdx.x * blockDim.x + threadIdx.x;
    if (n >= N_NODES) return;
    int d = 1;  // self loop
    #pragma unroll
    for (int xc = 0; xc < NXCD; ++xc) d += degX[xc * PAD + n];
    float di = rsqrtf((float)d);
    dinv[n] = di;
    t[n] = di * s[n];
}

// ---------------------------------------------------------------------------
// K3: scatter u[dst] += t[src], one pass, atomics into XCD-local shard.
// Per thread: one int4 of dst + one of src, 4 independent t-gathers (L2:
// t is 400 KB, read-shared -> replicated in every XCD's L2).
// ---------------------------------------------------------------------------
__global__ void __launch_bounds__(1024) k3_scatter(const int4* __restrict__ src4,
                                                   const int4* __restrict__ dst4,
                                                   const float* __restrict__ t,
                                                   float* __restrict__ uX) {
    int gid = blockIdx.x * 1024 + threadIdx.x;
    if (gid >= EQ4) return;
    int4 d4 = dst4[gid];
    int4 s4 = src4[gid];
    float t0 = t[s4.x], t1 = t[s4.y], t2 = t[s4.z], t3 = t[s4.w];
    float* myu = uX + xcc_id() * PAD;
    atomicAdd(&myu[d4.x], t0);
    atomicAdd(&myu[d4.y], t1);
    atomicAdd(&myu[d4.z], t2);
    atomicAdd(&myu[d4.w], t3);
}

// ---------------------------------------------------------------------------
// K4: merge 8 u shards + self-loop term + bias + sigmoid.
// ---------------------------------------------------------------------------
__global__ void k4_final(const float* __restrict__ uX,
                         const float* __restrict__ dinv,
                         const float* __restrict__ s,
                         const float* __restrict__ b,
                         const float* __restrict__ w2,
                         const float* __restrict__ b2,
                         float* __restrict__ out) {
    float c = b2[0];
    #pragma unroll 8
    for (int j = 0; j < HIDDEN; ++j) c += b[j] * w2[j];
    int n = blockIdx.x * blockDim.x + threadIdx.x;
    if (n >= N_NODES) return;
    float u = 0.f;
    #pragma unroll
    for (int xc = 0; xc < NXCD; ++xc) u += uX[xc * PAD + n];
    float di = dinv[n];
    float pre = di * (u + di * s[n]) + c;
    out[n] = 1.f / (1.f + expf(-pre));
}

// ------------------------- fallback (R1, validated) -------------------------
__global__ void wv_kernel(const float* __restrict__ W, const float* __restrict__ b,
                          const float* __restrict__ w2, const float* __restrict__ b2,
                          float* __restrict__ v, float* __restrict__ c) {
    int i = threadIdx.x;
    float acc = 0.f;
    for (int j = 0; j < HIDDEN; ++j) acc += W[i * HIDDEN + j] * w2[j];
    v[i] = acc;
    if (i == 0) {
        float cc = b2[0];
        for (int j = 0; j < HIDDEN; ++j) cc += b[j] * w2[j];
        *c = cc;
    }
}
__global__ void s_kernel(const float* __restrict__ x, const float* __restrict__ v,
                         float* __restrict__ s) {
    const int wave = threadIdx.x >> 6;
    const int lane = threadIdx.x & 63;
    const int n = blockIdx.x * 4 + wave;
    const float4* xr = (const float4*)(x + (size_t)n * IN_DIM);
    const float4* vr = (const float4*)v;
    float4 a  = xr[lane];
    float4 vv = vr[lane];
    float d = a.x * vv.x + a.y * vv.y + a.z * vv.z + a.w * vv.w;
    #pragma unroll
    for (int off = 32; off > 0; off >>= 1) d += __shfl_down(d, off, 64);
    if (lane == 0) s[n] = d;
}
__global__ void deg_kernel(const int* __restrict__ dst, int* __restrict__ cnt) {
    int e = blockIdx.x * blockDim.x + threadIdx.x;
    if (e < N_EDGES) atomicAdd(&cnt[dst[e]], 1);
}
__global__ void dinv_kernel(const int* __restrict__ cnt, const float* __restrict__ s,
                            float* __restrict__ dinv, float* __restrict__ t) {
    int n = blockIdx.x * blockDim.x + threadIdx.x;
    if (n < N_NODES) {
        float di = rsqrtf((float)(cnt[n] + 1));
        dinv[n] = di;
        t[n] = di * s[n];
    }
}
__global__ void scatter_kernel(const int* __restrict__ src, const int* __restrict__ dst,
                               const float* __restrict__ t, float* __restrict__ u) {
    int e = blockIdx.x * blockDim.x + threadIdx.x;
    if (e < N_EDGES) atomicAdd(&u[dst[e]], t[src[e]]);
}
__global__ void final_kernel(const float* __restrict__ dinv, const float* __restrict__ u,
                             const float* __restrict__ s, const float* __restrict__ c,
                             float* __restrict__ out) {
    int n = blockIdx.x * blockDim.x + threadIdx.x;
    if (n < N_NODES) {
        float di = dinv[n];
        float pre = di * (u[n] + di * s[n]) + c[0];
        out[n] = 1.f / (1.f + expf(-pre));
    }
}
// ----------------------------------------------------------------------------

extern "C" void kernel_launch(void* const* d_in, const int* in_sizes, int n_in,
                              void* d_out, int out_size, void* d_ws, size_t ws_size,
                              hipStream_t stream) {
    const float* x   = (const float*)d_in[0];   // [N, 256]
    const int*   ei  = (const int*)  d_in[1];   // [2, E]: src then dst
    const float* W   = (const float*)d_in[2];   // [256, 64]
    const float* b   = (const float*)d_in[3];   // [64]
    const float* w2  = (const float*)d_in[4];   // [64]
    const float* b2  = (const float*)d_in[5];   // [1]
    float* out = (float*)d_out;

    const int* src = ei;
    const int* dst = ei + N_EDGES;

    float* ws   = (float*)d_ws;
    float* s    = ws + 0;          // 100352
    float* t    = ws + 100352;     // 100352
    float* dinv = ws + 200704;     // 100352
    float* uX   = ws + 301056;     // 8 * 100352 floats (zeroed)
    int*   degX = (int*)(ws + 301056 + NXCD * PAD);  // 8 * 100352 ints (zeroed)
    const size_t need_bytes = (size_t)(301056 + 2 * NXCD * PAD) * 4;  // ~7.6 MB

    if (ws_size >= need_bytes) {
        // zero the 16 shards (6.4 MB) in one async memset
        hipMemsetAsync((char*)d_ws + (size_t)301056 * 4, 0,
                       (size_t)(2 * NXCD * PAD) * 4, stream);
        k1_deg_s<<<512, 1024, 0, stream>>>(x, W, w2, (const int4*)dst, degX, s);
        k2_deg_merge<<<(N_NODES + 511) / 512, 512, 0, stream>>>(degX, s, dinv, t);
        k3_scatter<<<(EQ4 + 1023) / 1024, 1024, 0, stream>>>((const int4*)src,
                                                             (const int4*)dst, t, uX);
        k4_final<<<(N_NODES + 511) / 512, 512, 0, stream>>>(uX, dinv, s, b, w2, b2, out);
    } else {
        // fallback: validated device-atomic path
        float* v   = ws + 0;
        float* c   = ws + 256;
        float* sf  = ws + 512;
        float* tf  = ws + 100608;
        float* df  = ws + 200704;
        float* u   = ws + 300800;
        int*   cnt = (int*)(ws + 400800);
        hipMemsetAsync((char*)d_ws + (size_t)300800 * 4, 0, (size_t)200000 * 4, stream);
        wv_kernel<<<1, 256, 0, stream>>>(W, b, w2, b2, v, c);
        s_kernel<<<N_NODES / 4, 256, 0, stream>>>(x, v, sf);
        deg_kernel<<<(N_EDGES + 255) / 256, 256, 0, stream>>>(dst, cnt);
        dinv_kernel<<<(N_NODES + 255) / 256, 256, 0, stream>>>(cnt, sf, df, tf);
        scatter_kernel<<<(N_EDGES + 255) / 256, 256, 0, stream>>>(src, dst, tf, u);
        final_kernel<<<(N_NODES + 255) / 256, 256, 0, stream>>>(df, u, sf, (ws + 256), out);
    }
}

// Round 8
// 202.663 us; speedup vs baseline: 2.0281x; 1.5127x over previous
//
#include <hip/hip_runtime.h>
#include <math.h>

#define N_NODES 100000
#define N_EDGES 1600000
#define IN_DIM  256
#define HIDDEN  64

// ---- fusedA geometry: 512 blocks x 1024 thr ---------------------------------
// deg: 128 blocks = 32 chunks x 4 ranges (byte-packed, LDS 25.6 KB)
#define D_CH    32
#define D_QPB   12500      // int4 groups per chunk (50000 edges)
#define D_PR    4
#define D_DNR   25600
#define D_DW    6400       // packed words per range
#define DEGB    128
// scatter: 256 blocks = 32 chunks x 8 ranges (LDS 50,176 B)
#define S_CH    32
#define S_QPB   12500
#define S_SR    8
#define S_RANGE 12544

// ---------------------------------------------------------------------------
// K_A (fused): blocks [0,128) byte-packed degree histograms;
// blocks [128,512) compute v = W.w2 in LDS then stream s[n] = x[n].v
// (wave per 1 KiB row). s gets 3/4 of the machine -> near-full HBM BW.
// ---------------------------------------------------------------------------
__global__ void __launch_bounds__(1024) fusedA_kernel(const float* __restrict__ x,
                                                      const float* __restrict__ W,
                                                      const float* __restrict__ w2,
                                                      const int4* __restrict__ dst4,
                                                      unsigned* __restrict__ partialD,
                                                      float* __restrict__ s) {
    __shared__ __align__(16) unsigned sh[D_DW];   // 25.6 KB (deg) / v (s-role)
    const int bid = blockIdx.x, tid = threadIdx.x;
    if (bid < DEGB) {
        const int r  = bid & (D_PR - 1);
        const int bb = bid >> 2;
        const int nbase = r * D_DNR;
        for (int i = tid; i < D_DW; i += 1024) sh[i] = 0u;
        __syncthreads();
        const int q0 = bb * D_QPB;
        for (int k = tid; k < D_QPB; k += 1024) {
            int4 d4 = dst4[q0 + k];
            int d0 = d4.x - nbase, d1 = d4.y - nbase, d2 = d4.z - nbase, d3 = d4.w - nbase;
            if ((unsigned)d0 < (unsigned)D_DNR) atomicAdd(&sh[d0 >> 2], 1u << ((d0 & 3) * 8));
            if ((unsigned)d1 < (unsigned)D_DNR) atomicAdd(&sh[d1 >> 2], 1u << ((d1 & 3) * 8));
            if ((unsigned)d2 < (unsigned)D_DNR) atomicAdd(&sh[d2 >> 2], 1u << ((d2 & 3) * 8));
            if ((unsigned)d3 < (unsigned)D_DNR) atomicAdd(&sh[d3 >> 2], 1u << ((d3 & 3) * 8));
        }
        __syncthreads();
        unsigned* outp = partialD + (size_t)bid * D_DW;
        for (int i = tid; i < D_DW; i += 1024) outp[i] = sh[i];
    } else {
        float* vsh = (float*)sh;
        if (tid < IN_DIM) {
            const float4* wr  = (const float4*)(W + tid * HIDDEN);
            const float4* w2r = (const float4*)w2;
            float acc = 0.f;
            #pragma unroll
            for (int j = 0; j < HIDDEN / 4; ++j) {
                float4 a = wr[j], q = w2r[j];
                acc += a.x * q.x + a.y * q.y + a.z * q.z + a.w * q.w;
            }
            vsh[tid] = acc;
        }
        __syncthreads();
        const int wid  = tid >> 6;
        const int lane = tid & 63;
        float4 vv = ((const float4*)vsh)[lane];
        for (int n = (bid - DEGB) * 16 + wid; n < N_NODES; n += 384 * 16) {
            const float4* xr = (const float4*)(x + (size_t)n * IN_DIM);
            float4 a = xr[lane];
            float d = a.x * vv.x + a.y * vv.y + a.z * vv.z + a.w * vv.w;
            #pragma unroll
            for (int off = 32; off > 0; off >>= 1) d += __shfl_down(d, off, 64);
            if (lane == 0) s[n] = d;
        }
    }
}

// ---------------------------------------------------------------------------
// K_B: merge byte-packed degree partials; fuse dinv = rsqrt(deg+1), t = dinv*s.
// One thread per packed word (4 nodes), coalesced over j.
// ---------------------------------------------------------------------------
__global__ void deg_merge_kernel(const unsigned* __restrict__ partialD,
                                 const float* __restrict__ s,
                                 float* __restrict__ dinv, float* __restrict__ t) {
    int w = blockIdx.x * blockDim.x + threadIdx.x;
    if (w >= N_NODES / 4) return;              // 25000 words cover all nodes
    const int r = w / D_DW, j = w - r * D_DW;
    unsigned a0 = 0, a1 = 0, a2 = 0, a3 = 0;
    #pragma unroll 8
    for (int bb = 0; bb < D_CH; ++bb) {
        unsigned p = partialD[(size_t)(bb * D_PR + r) * D_DW + j];
        a0 += p & 255u; a1 += (p >> 8) & 255u; a2 += (p >> 16) & 255u; a3 += p >> 24;
    }
    const int n0 = w * 4;                      // == r*D_DNR + j*4
    float4 sv = *(const float4*)(s + n0);
    float4 di, tv;
    di.x = rsqrtf((float)(a0 + 1)); di.y = rsqrtf((float)(a1 + 1));
    di.z = rsqrtf((float)(a2 + 1)); di.w = rsqrtf((float)(a3 + 1));
    tv.x = di.x * sv.x; tv.y = di.y * sv.y; tv.z = di.z * sv.z; tv.w = di.w * sv.w;
    *(float4*)(dinv + n0) = di;
    *(float4*)(t + n0) = tv;
}

// ---------------------------------------------------------------------------
// K_C: scatter u[dst] += t[src] via LDS-private accumulators (validated R5).
// 256 blocks x 1024 threads.
// ---------------------------------------------------------------------------
__global__ void __launch_bounds__(1024) scat_hist_kernel(const int4* __restrict__ src4,
                                                         const int4* __restrict__ dst4,
                                                         const float* __restrict__ t,
                                                         float* __restrict__ partialU) {
    __shared__ float acc[S_RANGE];
    const int r  = blockIdx.x & (S_SR - 1);
    const int bb = blockIdx.x >> 3;
    const int nbase = r * S_RANGE;
    for (int i = threadIdx.x; i < S_RANGE; i += 1024) acc[i] = 0.f;
    __syncthreads();
    const int q0 = bb * S_QPB;
    for (int k = threadIdx.x; k < S_QPB; k += 1024) {
        int4 d4 = dst4[q0 + k];
        int4 s4 = src4[q0 + k];
        int d0 = d4.x - nbase, d1 = d4.y - nbase, d2 = d4.z - nbase, d3 = d4.w - nbase;
        if ((unsigned)d0 < (unsigned)S_RANGE) atomicAdd(&acc[d0], t[s4.x]);
        if ((unsigned)d1 < (unsigned)S_RANGE) atomicAdd(&acc[d1], t[s4.y]);
        if ((unsigned)d2 < (unsigned)S_RANGE) atomicAdd(&acc[d2], t[s4.z]);
        if ((unsigned)d3 < (unsigned)S_RANGE) atomicAdd(&acc[d3], t[s4.w]);
    }
    __syncthreads();
    float* outp = partialU + (size_t)blockIdx.x * S_RANGE;
    for (int i = threadIdx.x; i < S_RANGE; i += 1024) outp[i] = acc[i];
}

// ---------------------------------------------------------------------------
// K_D: merge scatter partials + sigmoid, float4 (4 nodes/thread).
// ---------------------------------------------------------------------------
__global__ void merge_final_kernel(const float* __restrict__ partialU,
                                   const float* __restrict__ dinv,
                                   const float* __restrict__ s,
                                   const float* __restrict__ b,
                                   const float* __restrict__ w2,
                                   const float* __restrict__ b2,
                                   float* __restrict__ out) {
    float c = b2[0];
    #pragma unroll 8
    for (int j = 0; j < HIDDEN; ++j) c += b[j] * w2[j];
    int g = blockIdx.x * blockDim.x + threadIdx.x;   // one thread = 4 nodes
    if (g >= N_NODES / 4) return;
    const int n0 = g * 4;
    const int r = n0 / S_RANGE, j = n0 - r * S_RANGE;  // j is 4-aligned
    float4 u = make_float4(0.f, 0.f, 0.f, 0.f);
    #pragma unroll 8
    for (int bl = 0; bl < S_CH; ++bl) {
        float4 p = *(const float4*)(partialU + (size_t)(bl * S_SR + r) * S_RANGE + j);
        u.x += p.x; u.y += p.y; u.z += p.z; u.w += p.w;
    }
    float4 di = *(const float4*)(dinv + n0);
    float4 sv = *(const float4*)(s + n0);
    float4 o;
    o.x = 1.f / (1.f + expf(-(di.x * (u.x + di.x * sv.x) + c)));
    o.y = 1.f / (1.f + expf(-(di.y * (u.y + di.y * sv.y) + c)));
    o.z = 1.f / (1.f + expf(-(di.z * (u.z + di.z * sv.z) + c)));
    o.w = 1.f / (1.f + expf(-(di.w * (u.w + di.w * sv.w) + c)));
    *(float4*)(out + n0) = o;
}

// ------------------------- fallback (R1, validated) -------------------------
__global__ void wv_kernel(const float* __restrict__ W, const float* __restrict__ b,
                          const float* __restrict__ w2, const float* __restrict__ b2,
                          float* __restrict__ v, float* __restrict__ c) {
    int i = threadIdx.x;
    float acc = 0.f;
    for (int j = 0; j < HIDDEN; ++j) acc += W[i * HIDDEN + j] * w2[j];
    v[i] = acc;
    if (i == 0) {
        float cc = b2[0];
        for (int j = 0; j < HIDDEN; ++j) cc += b[j] * w2[j];
        *c = cc;
    }
}
__global__ void s_kernel(const float* __restrict__ x, const float* __restrict__ v,
                         float* __restrict__ s) {
    const int wave = threadIdx.x >> 6;
    const int lane = threadIdx.x & 63;
    const int n = blockIdx.x * 4 + wave;
    const float4* xr = (const float4*)(x + (size_t)n * IN_DIM);
    const float4* vr = (const float4*)v;
    float4 a  = xr[lane];
    float4 vv = vr[lane];
    float d = a.x * vv.x + a.y * vv.y + a.z * vv.z + a.w * vv.w;
    #pragma unroll
    for (int off = 32; off > 0; off >>= 1) d += __shfl_down(d, off, 64);
    if (lane == 0) s[n] = d;
}
__global__ void deg_kernel(const int* __restrict__ dst, int* __restrict__ cnt) {
    int e = blockIdx.x * blockDim.x + threadIdx.x;
    if (e < N_EDGES) atomicAdd(&cnt[dst[e]], 1);
}
__global__ void dinv_kernel(const int* __restrict__ cnt, const float* __restrict__ s,
                            float* __restrict__ dinv, float* __restrict__ t) {
    int n = blockIdx.x * blockDim.x + threadIdx.x;
    if (n < N_NODES) {
        float di = rsqrtf((float)(cnt[n] + 1));
        dinv[n] = di;
        t[n] = di * s[n];
    }
}
__global__ void scatter_kernel(const int* __restrict__ src, const int* __restrict__ dst,
                               const float* __restrict__ t, float* __restrict__ u) {
    int e = blockIdx.x * blockDim.x + threadIdx.x;
    if (e < N_EDGES) atomicAdd(&u[dst[e]], t[src[e]]);
}
__global__ void final_kernel(const float* __restrict__ dinv, const float* __restrict__ u,
                             const float* __restrict__ s, const float* __restrict__ c,
                             float* __restrict__ out) {
    int n = blockIdx.x * blockDim.x + threadIdx.x;
    if (n < N_NODES) {
        float di = dinv[n];
        float pre = di * (u[n] + di * s[n]) + c[0];
        out[n] = 1.f / (1.f + expf(-pre));
    }
}
// ----------------------------------------------------------------------------

extern "C" void kernel_launch(void* const* d_in, const int* in_sizes, int n_in,
                              void* d_out, int out_size, void* d_ws, size_t ws_size,
                              hipStream_t stream) {
    const float* x   = (const float*)d_in[0];   // [N, 256]
    const int*   ei  = (const int*)  d_in[1];   // [2, E]: src then dst
    const float* W   = (const float*)d_in[2];   // [256, 64]
    const float* b   = (const float*)d_in[3];   // [64]
    const float* w2  = (const float*)d_in[4];   // [64]
    const float* b2  = (const float*)d_in[5];   // [1]
    float* out = (float*)d_out;

    const int* src = ei;
    const int* dst = ei + N_EDGES;

    float* ws = (float*)d_ws;
    float*    s        = ws + 0;          // 100352
    float*    t        = ws + 100352;     // 100352
    float*    dinv     = ws + 200704;     // 100352
    unsigned* partialD = (unsigned*)(ws + 301056);  // 128*6400  =   819,200 words (3.3 MB)
    float*    partialU = ws + 1120256;              // 256*12544 = 3,211,264 floats (12.8 MB)
    const size_t need_bytes = (size_t)(1120256 + 256 * S_RANGE) * 4;  // ~17.3 MB

    if (ws_size >= need_bytes) {
        fusedA_kernel<<<512, 1024, 0, stream>>>(x, W, w2, (const int4*)dst, partialD, s);
        deg_merge_kernel<<<(N_NODES / 4 + 255) / 256, 256, 0, stream>>>(partialD, s, dinv, t);
        scat_hist_kernel<<<S_CH * S_SR, 1024, 0, stream>>>((const int4*)src,
                                                           (const int4*)dst, t, partialU);
        merge_final_kernel<<<(N_NODES / 4 + 255) / 256, 256, 0, stream>>>(partialU, dinv, s,
                                                                          b, w2, b2, out);
    } else {
        // fallback: validated device-atomic path
        float* v   = ws + 0;
        float* c   = ws + 256;
        float* sf  = ws + 512;
        float* tf  = ws + 100608;
        float* df  = ws + 200704;
        float* u   = ws + 300800;
        int*   cnt = (int*)(ws + 400800);
        hipMemsetAsync((char*)d_ws + (size_t)300800 * 4, 0, (size_t)200000 * 4, stream);
        wv_kernel<<<1, 256, 0, stream>>>(W, b, w2, b2, v, c);
        s_kernel<<<N_NODES / 4, 256, 0, stream>>>(x, v, sf);
        deg_kernel<<<(N_EDGES + 255) / 256, 256, 0, stream>>>(dst, cnt);
        dinv_kernel<<<(N_NODES + 255) / 256, 256, 0, stream>>>(cnt, sf, df, tf);
        scatter_kernel<<<(N_EDGES + 255) / 256, 256, 0, stream>>>(src, dst, tf, u);
        final_kernel<<<(N_NODES + 255) / 256, 256, 0, stream>>>(df, u, sf, c, out);
    }
}